// Round 13
// baseline (170.275 us; speedup 1.0000x reference)
//
#include <hip/hip_runtime.h>
#include <hip/hip_bf16.h>

#define NN 4096      // n_nodes
#define FIN 1433     // in features
#define NH 8         // heads
#define DH 8         // per-head dim
#define HD 64        // NH*DH
#define KP 1472      // K padded to 46*32
#define LOG2E 1.44269504f
#define NJS 8        // j-splits
#define NCHK ((NN / NJS) / 128)   // 4 chunks of 128 j

typedef unsigned int u32;
typedef unsigned long long u64;
typedef float v4f __attribute__((ext_vector_type(4)));
typedef _Float16 f16;
typedef _Float16 h2 __attribute__((ext_vector_type(2)));
typedef _Float16 f16x8 __attribute__((ext_vector_type(8)));

static __device__ __forceinline__ short f2h16(float f) {
    union { f16 h; short s; } u; u.h = (f16)f; return u.s;
}
static __device__ __forceinline__ h2 u2h2(u32 x) {
    union { u32 u; h2 h; } v; v.u = x; return v.h;
}
static __device__ __forceinline__ u32 h22u(h2 x) {
    union { h2 h; u32 u; } v; v.h = x; return v.u;
}

#if __has_builtin(__builtin_amdgcn_sbfe)
#define SBFE1(x, k) __builtin_amdgcn_sbfe((int)(x), (k), 1)
#else
#define SBFE1(x, k) (((int)((x) << (31 - (k)))) >> 31)
#endif

// ---------------- kernel 0: Wt[n][k] = f16(W[k][n]), k zero-padded to 1472 ---
__global__ __launch_bounds__(256) void k_wprep(const float* __restrict__ W,
                                               short* __restrict__ Wt) {
    __shared__ float Ts[64][65];
    const int c = blockIdx.x;
    const int u = threadIdx.x;
    const int n4 = (u & 15) * 4;
    const int kr = u >> 4;
#pragma unroll
    for (int q = 0; q < 4; ++q) {
        const int kl = kr + q * 16;
        const int kg = c * 64 + kl;
        v4f v = {0.f, 0.f, 0.f, 0.f};
        if (kg < FIN) v = *(const v4f*)&W[(size_t)kg * HD + n4];
        *(v4f*)&Ts[kl][n4] = v;
    }
    __syncthreads();
    const int n = u >> 2;
    const int koff = (u & 3) * 16;
    __align__(16) short tmp[16];
#pragma unroll
    for (int r = 0; r < 16; ++r) tmp[r] = f2h16(Ts[koff + r][n]);
    *(uint4*)&Wt[(size_t)n * KP + c * 64 + koff]     = *(uint4*)&tmp[0];
    *(uint4*)&Wt[(size_t)n * KP + c * 64 + koff + 8] = *(uint4*)&tmp[8];
}

// ---------------- kernel 1: g = vert @ W via f16 MFMA, barrier-free K-split --
// Epilogue: gT[hd][node] f16; eB[h][node]=exp(sr) f16; eD=exp(0.2sr) f16;
// Rw[node][h]=exp(-0.8 sl) f32.
__global__ __launch_bounds__(256, 4) void k_gemm(
    const float* __restrict__ vert, const short* __restrict__ Wt,
    const float* __restrict__ al, const float* __restrict__ ar,
    short* __restrict__ gT, short* __restrict__ eB, short* __restrict__ eD,
    float* __restrict__ Rw)
{
    __shared__ float cacc[4][16][64];   // 16 KB

    const int t = threadIdx.x, lane = t & 63, w = t >> 6;
    const int ml = lane & 15, q = lane >> 4;
    const int i0 = blockIdx.x * 16;
    const float* vrow = vert + (size_t)(i0 + ml) * FIN;

    v4f acc[4];
#pragma unroll
    for (int g = 0; g < 4; ++g) acc[g] = (v4f){0.f, 0.f, 0.f, 0.f};

    for (int c = w; c < 45; c += 4) {
        const int k0 = c * 32 + q * 8;
        v4f a0, a1;
        if (k0 + 7 < FIN) {
            a0 = *(const v4f*)&vrow[k0];
            a1 = *(const v4f*)&vrow[k0 + 4];
        } else {
            float tmp[8];
#pragma unroll
            for (int e = 0; e < 8; ++e)
                tmp[e] = (k0 + e < FIN) ? vrow[k0 + e] : 0.f;
            a0 = (v4f){tmp[0], tmp[1], tmp[2], tmp[3]};
            a1 = (v4f){tmp[4], tmp[5], tmp[6], tmp[7]};
        }
        const f16x8 af = {(f16)a0.x, (f16)a0.y, (f16)a0.z, (f16)a0.w,
                          (f16)a1.x, (f16)a1.y, (f16)a1.z, (f16)a1.w};
#pragma unroll
        for (int g = 0; g < 4; ++g) {
            const f16x8 bf = *(const f16x8*)&Wt[(size_t)(g * 16 + ml) * KP + k0];
            acc[g] = __builtin_amdgcn_mfma_f32_16x16x32_f16(af, bf, acc[g], 0, 0, 0);
        }
    }

#pragma unroll
    for (int g = 0; g < 4; ++g)
#pragma unroll
        for (int r = 0; r < 4; ++r)
            cacc[w][q * 4 + r][g * 16 + ml] = acc[g][r];
    __syncthreads();

    const int m = t >> 4, n4 = (t & 15) * 4;
    v4f s = (v4f){0.f, 0.f, 0.f, 0.f};
#pragma unroll
    for (int ww = 0; ww < 4; ++ww) s += *(const v4f*)&cacc[ww][m][n4];

#pragma unroll
    for (int e = 0; e < 4; ++e)        // transposed store: gT[hd][node]
        gT[(size_t)(n4 + e) * NN + i0 + m] = f2h16(s[e]);

    float pl = s.x * al[n4] + s.y * al[n4 + 1] + s.z * al[n4 + 2] + s.w * al[n4 + 3];
    float pr = s.x * ar[n4] + s.y * ar[n4 + 1] + s.z * ar[n4 + 2] + s.w * ar[n4 + 3];
    pl += __shfl_xor(pl, 1, 64);
    pr += __shfl_xor(pr, 1, 64);
    if ((t & 1) == 0) {
        const int h = (t & 15) >> 1;
        const int node = i0 + m;
        eB[h * NN + node] = f2h16(exp2f(pr * LOG2E));          // exp(sr)
        eD[h * NN + node] = f2h16(exp2f(0.2f * pr * LOG2E));   // exp(0.2 sr)
        Rw[node * NH + h] = exp2f(-0.8f * pl * LOG2E);         // exp(-0.8 sl)
    }
}

// ---------------- kernel 2: MFMA flash-attn, fp16-pk, ITILE=2, NJS=8 ---------
// grid (128, 2, 8): x = 32-row i-block, y = h-group, z = j-split (512 j each).
// P'[i,j] = max(B_j, R_i*D_j) (= exp(leaky(sl+sr))/A_i; row scale cancels in
// num/den). Masks via even/odd-j ballots -> sbfe sign-smear + v_perm select.
// launch_bounds(256,6): 6 blocks/CU (LDS 24.6KB caps there), VGPR<=85 budget.
__global__ __launch_bounds__(256, 6) void k_attn(
    const int* __restrict__ edge, const short* __restrict__ gT,
    const short* __restrict__ eB, const short* __restrict__ eD,
    const float* __restrict__ Rw,
    float* __restrict__ numw, float* __restrict__ denw)
{
    __shared__ __align__(16) short Gt[2][33][136];  // 32 G-dims + ones row, fp16
    __shared__ __align__(16) short sB[2][4][136];   // exp(sr) fp16
    __shared__ __align__(16) short sD[2][4][136];   // exp(0.2 sr) fp16
    __shared__ u32 mA[2][32][4];                    // even-j mask words per row
    __shared__ u32 mB[2][32][4];                    // odd-j (pad to 4)

    const int t = threadIdx.x, lane = t & 63, w = t >> 6;
    const int ml = lane & 15, quad = lane >> 4;
    const int i0 = blockIdx.x * 32;
    const int hg = blockIdx.y, js = blockIdx.z;
    const int jbase = js * (NN / NJS);
    const int h = hg * 4 + w;

    h2 Ri[2];
#pragma unroll
    for (int it = 0; it < 2; ++it) {
        const f16 rh = (f16)Rw[(i0 + it * 16 + ml) * NH + h];
        Ri[it] = (h2){rh, rh};
    }

    if (t < 136) { Gt[0][32][t] = 0x3C00; Gt[1][32][t] = 0x3C00; }  // fp16 1.0

    const short* gTh = gT + (hg * 32) * NN;
    const short* eBh = eB + (hg * 4) * NN;
    const short* eDh = eD + (hg * 4) * NN;

    const int grow = t >> 3, gseg = (t & 7) * 16;   // G: 32 rows x 128 f16
    const int bh = (t >> 3) & 3, bseg = (t & 7) * 16;  // B/D: 4 heads x 128 f16

    {   // stage chunk 0 (everything before compute)
        const int j0 = jbase;
        const uint4 g0 = *(const uint4*)&gTh[grow * NN + j0 + gseg];
        const uint4 g1 = *(const uint4*)&gTh[grow * NN + j0 + gseg + 8];
        *(uint4*)&Gt[0][grow][gseg]     = g0;
        *(uint4*)&Gt[0][grow][gseg + 8] = g1;
        if (t < 32) {
            *(uint4*)&sB[0][bh][bseg]     = *(const uint4*)&eBh[bh * NN + j0 + bseg];
            *(uint4*)&sB[0][bh][bseg + 8] = *(const uint4*)&eBh[bh * NN + j0 + bseg + 8];
        } else if (t < 64) {
            *(uint4*)&sD[0][bh][bseg]     = *(const uint4*)&eDh[bh * NN + j0 + bseg];
            *(uint4*)&sD[0][bh][bseg + 8] = *(const uint4*)&eDh[bh * NN + j0 + bseg + 8];
        }
#pragma unroll
        for (int rr = 0; rr < 8; ++rr) {
            const int row = w * 8 + rr;
            const int2 e2 = *(const int2*)&edge[(i0 + row) * NN + j0 + 2 * lane];
            const u64 bA = __ballot(e2.x != 0);
            const u64 bB = __ballot(e2.y != 0);
            if (lane == 0)  { mA[0][row][0] = (u32)bA;         mB[0][row][0] = (u32)bB; }
            if (lane == 32) { mA[0][row][1] = (u32)(bA >> 32); mB[0][row][1] = (u32)(bB >> 32); }
        }
    }
    __syncthreads();

    v4f acc[2];
    acc[0] = (v4f){0.f, 0.f, 0.f, 0.f};
    acc[1] = (v4f){0.f, 0.f, 0.f, 0.f};

    const int qb4 = quad * 4;
    const int browv = (ml < 8) ? (w * 8 + ml) : 32;

    for (int c = 0; c < NCHK; ++c) {
        const int cb = c & 1, nb = cb ^ 1;
        const bool pf = (c + 1) < NCHK;
        uint4 pg0, pg1, pbd0, pbd1; int2 pe[8];
        if (pf) {   // prefetch next chunk IN FULL (G + B/D + all edge rows)
            const int j0 = jbase + (c + 1) * 128;
            pg0 = *(const uint4*)&gTh[grow * NN + j0 + gseg];
            pg1 = *(const uint4*)&gTh[grow * NN + j0 + gseg + 8];
            if (t < 32) {
                pbd0 = *(const uint4*)&eBh[bh * NN + j0 + bseg];
                pbd1 = *(const uint4*)&eBh[bh * NN + j0 + bseg + 8];
            } else if (t < 64) {
                pbd0 = *(const uint4*)&eDh[bh * NN + j0 + bseg];
                pbd1 = *(const uint4*)&eDh[bh * NN + j0 + bseg + 8];
            }
#pragma unroll
            for (int rr = 0; rr < 8; ++rr)
                pe[rr] = *(const int2*)&edge[(i0 + w * 8 + rr) * NN + j0 + 2 * lane];
        }
        // ---- compute on buffer cb ----
        uint2 wa[2], wb[2];
#pragma unroll
        for (int it = 0; it < 2; ++it) {
            wa[it] = *(const uint2*)&mA[cb][it * 16 + ml][0];
            wb[it] = *(const uint2*)&mB[cb][it * 16 + ml][0];
        }
#pragma unroll
        for (int s = 0; s < 4; ++s) {
            const uint4 bu = *(const uint4*)&sB[cb][w][s * 32 + quad * 8];
            const uint4 du = *(const uint4*)&sD[cb][w][s * 32 + quad * 8];
            const uint4 gu = *(const uint4*)&Gt[cb][browv][s * 32 + quad * 8];
            union { uint4 u; f16x8 h; } gub; gub.u = gu;
            const f16x8 bfrag = gub.h;
            const int base = ((s & 1) << 4) + qb4;
#pragma unroll
            for (int it = 0; it < 2; ++it) {
                const u32 WA = ((s >> 1) ? wa[it].y : wa[it].x) >> base;
                const u32 WB = ((s >> 1) ? wb[it].y : wb[it].x) >> base;
                u32 aw[4];
#pragma unroll
                for (int k = 0; k < 4; ++k) {
                    const int ea = SBFE1(WA, k);            // 0 or 0xFFFFFFFF
                    const int eb = SBFE1(WB, k);
                    const u32 m = __builtin_amdgcn_perm((u32)eb, (u32)ea, 0x05040100u);
                    const u32 rd = h22u(Ri[it] * u2h2((&du.x)[k]));   // v_pk_mul_f16
                    u32 pm;
                    asm("v_pk_max_f16 %0, %1, %2" : "=v"(pm) : "v"(rd), "v"((&bu.x)[k]));
                    aw[k] = pm & m;
                }
                union { uint4 u; f16x8 h; } aub;
                aub.u = (uint4){aw[0], aw[1], aw[2], aw[3]};
                acc[it] = __builtin_amdgcn_mfma_f32_16x16x32_f16(aub.h, bfrag, acc[it], 0, 0, 0);
            }
        }
        if (pf) {   // drain prefetched registers into buffer nb (no new loads)
            *(uint4*)&Gt[nb][grow][gseg]     = pg0;
            *(uint4*)&Gt[nb][grow][gseg + 8] = pg1;
            if (t < 32) {
                *(uint4*)&sB[nb][bh][bseg]     = pbd0;
                *(uint4*)&sB[nb][bh][bseg + 8] = pbd1;
            } else if (t < 64) {
                *(uint4*)&sD[nb][bh][bseg]     = pbd0;
                *(uint4*)&sD[nb][bh][bseg + 8] = pbd1;
            }
#pragma unroll
            for (int rr = 0; rr < 8; ++rr) {
                const int row = w * 8 + rr;
                const u64 bA = __ballot(pe[rr].x != 0);
                const u64 bB = __ballot(pe[rr].y != 0);
                if (lane == 0)  { mA[nb][row][0] = (u32)bA;         mB[nb][row][0] = (u32)bB; }
                if (lane == 32) { mA[nb][row][1] = (u32)(bA >> 32); mB[nb][row][1] = (u32)(bB >> 32); }
            }
        }
        __syncthreads();
    }

    // C layout: col = ml (0..7 dims, 8 = denominator), row = quad*4 + r
    float* nw = numw + (size_t)js * NN * HD;
    float* dw = denw + (size_t)js * NN * NH;
#pragma unroll
    for (int it = 0; it < 2; ++it) {
        const int ibase = i0 + it * 16 + quad * 4;
#pragma unroll
        for (int r = 0; r < 4; ++r) {
            if (ml < 8)       nw[(ibase + r) * HD + h * 8 + ml] = acc[it][r];
            else if (ml == 8) dw[(ibase + r) * NH + h]          = acc[it][r];
        }
    }
}

// ---------------- kernel 3: combine j-split partials, div, ELU ---------------
__global__ __launch_bounds__(256) void k_comb(
    const float* __restrict__ numw, const float* __restrict__ denw,
    float* __restrict__ out)
{
    const int gid = blockIdx.x * 256 + threadIdx.x;   // 0 .. NN*HD-1
    const int i = gid >> 6, h = (gid & 63) >> 3;
    float num = 0.f, den = 0.f;
#pragma unroll
    for (int s = 0; s < NJS; ++s) {
        num += numw[s * NN * HD + gid];
        den += denw[s * NN * NH + i * NH + h];
    }
    float x = num / den;
    out[gid] = (x > 0.f) ? x : (__expf(x) - 1.f);     // ELU
}

extern "C" void kernel_launch(void* const* d_in, const int* in_sizes, int n_in,
                              void* d_out, int out_size, void* d_ws, size_t ws_size,
                              hipStream_t stream) {
    const float* vert = (const float*)d_in[0];
    const int*   edge = (const int*)d_in[1];
    const float* W    = (const float*)d_in[2];
    const float* al   = (const float*)d_in[3];
    const float* ar   = (const float*)d_in[4];
    float* out = (float*)d_out;

    char* ws = (char*)d_ws;
    short* gT   = (short*)ws;                          // 512 KB f16 g^T
    short* eB   = (short*)(ws + 512 * 1024);           // 64 KB
    short* eD   = (short*)(ws + 576 * 1024);           // 64 KB
    float* Rw   = (float*)(ws + 640 * 1024);           // 128 KB
    short* Wt   = (short*)(ws + 768 * 1024);           // 184 KB
    float* numw = (float*)(ws + 1024 * 1024);          // 8 MB (8 splits)
    float* denw = (float*)(ws + 9 * 1024 * 1024);      // 1 MB

    hipLaunchKernelGGL(k_wprep, dim3(23), dim3(256), 0, stream, W, Wt);
    hipLaunchKernelGGL(k_gemm, dim3(NN / 16), dim3(256), 0, stream,
                       vert, Wt, al, ar, gT, eB, eD, Rw);
    hipLaunchKernelGGL(k_attn, dim3(NN / 32, 2, NJS), dim3(256), 0, stream,
                       edge, gT, eB, eD, Rw, numw, denw);
    hipLaunchKernelGGL(k_comb, dim3(NN * HD / 256), dim3(256), 0, stream,
                       numw, denw, out);
}

// Round 14
// 149.804 us; speedup vs baseline: 1.1367x; 1.1367x over previous
//
#include <hip/hip_runtime.h>
#include <hip/hip_bf16.h>

#define NN 4096      // n_nodes
#define FIN 1433     // in features
#define NH 8         // heads
#define DH 8         // per-head dim
#define HD 64        // NH*DH
#define KP 1472      // K padded to 46*32
#define LOG2E 1.44269504f
#define NJS 4        // j-splits
#define NCHK ((NN / NJS) / 128)   // 8 chunks of 128 j

typedef unsigned int u32;
typedef unsigned long long u64;
typedef float v4f __attribute__((ext_vector_type(4)));
typedef _Float16 f16;
typedef _Float16 h2 __attribute__((ext_vector_type(2)));
typedef _Float16 f16x8 __attribute__((ext_vector_type(8)));

static __device__ __forceinline__ short f2h16(float f) {
    union { f16 h; short s; } u; u.h = (f16)f; return u.s;
}
static __device__ __forceinline__ h2 u2h2(u32 x) {
    union { u32 u; h2 h; } v; v.u = x; return v.h;
}
static __device__ __forceinline__ u32 h22u(h2 x) {
    union { h2 h; u32 u; } v; v.h = x; return v.u;
}

#if __has_builtin(__builtin_amdgcn_sbfe)
#define SBFE1(x, k) __builtin_amdgcn_sbfe((int)(x), (k), 1)
#else
#define SBFE1(x, k) (((int)((x) << (31 - (k)))) >> 31)
#endif

// ---------------- kernel 0: Wt[n][k] = f16(W[k][n]), k zero-padded to 1472 ---
__global__ __launch_bounds__(256) void k_wprep(const float* __restrict__ W,
                                               short* __restrict__ Wt) {
    __shared__ float Ts[64][65];
    const int c = blockIdx.x;
    const int u = threadIdx.x;
    const int n4 = (u & 15) * 4;
    const int kr = u >> 4;
#pragma unroll
    for (int q = 0; q < 4; ++q) {
        const int kl = kr + q * 16;
        const int kg = c * 64 + kl;
        v4f v = {0.f, 0.f, 0.f, 0.f};
        if (kg < FIN) v = *(const v4f*)&W[(size_t)kg * HD + n4];
        *(v4f*)&Ts[kl][n4] = v;
    }
    __syncthreads();
    const int n = u >> 2;
    const int koff = (u & 3) * 16;
    __align__(16) short tmp[16];
#pragma unroll
    for (int r = 0; r < 16; ++r) tmp[r] = f2h16(Ts[koff + r][n]);
    *(uint4*)&Wt[(size_t)n * KP + c * 64 + koff]     = *(uint4*)&tmp[0];
    *(uint4*)&Wt[(size_t)n * KP + c * 64 + koff + 8] = *(uint4*)&tmp[8];
}

// ---------------- kernel 1: g = vert @ W via f16 MFMA, barrier-free K-split --
// Epilogue: gT[hd][node] f16; eB[h][node]=exp(sr) f16; eD=exp(0.2sr) f16;
// Rw[node][h]=exp(-0.8 sl) f32.
__global__ __launch_bounds__(256, 4) void k_gemm(
    const float* __restrict__ vert, const short* __restrict__ Wt,
    const float* __restrict__ al, const float* __restrict__ ar,
    short* __restrict__ gT, short* __restrict__ eB, short* __restrict__ eD,
    float* __restrict__ Rw)
{
    __shared__ float cacc[4][16][64];   // 16 KB

    const int t = threadIdx.x, lane = t & 63, w = t >> 6;
    const int ml = lane & 15, q = lane >> 4;
    const int i0 = blockIdx.x * 16;
    const float* vrow = vert + (size_t)(i0 + ml) * FIN;

    v4f acc[4];
#pragma unroll
    for (int g = 0; g < 4; ++g) acc[g] = (v4f){0.f, 0.f, 0.f, 0.f};

    for (int c = w; c < 45; c += 4) {
        const int k0 = c * 32 + q * 8;
        v4f a0, a1;
        if (k0 + 7 < FIN) {
            a0 = *(const v4f*)&vrow[k0];
            a1 = *(const v4f*)&vrow[k0 + 4];
        } else {
            float tmp[8];
#pragma unroll
            for (int e = 0; e < 8; ++e)
                tmp[e] = (k0 + e < FIN) ? vrow[k0 + e] : 0.f;
            a0 = (v4f){tmp[0], tmp[1], tmp[2], tmp[3]};
            a1 = (v4f){tmp[4], tmp[5], tmp[6], tmp[7]};
        }
        const f16x8 af = {(f16)a0.x, (f16)a0.y, (f16)a0.z, (f16)a0.w,
                          (f16)a1.x, (f16)a1.y, (f16)a1.z, (f16)a1.w};
#pragma unroll
        for (int g = 0; g < 4; ++g) {
            const f16x8 bf = *(const f16x8*)&Wt[(size_t)(g * 16 + ml) * KP + k0];
            acc[g] = __builtin_amdgcn_mfma_f32_16x16x32_f16(af, bf, acc[g], 0, 0, 0);
        }
    }

#pragma unroll
    for (int g = 0; g < 4; ++g)
#pragma unroll
        for (int r = 0; r < 4; ++r)
            cacc[w][q * 4 + r][g * 16 + ml] = acc[g][r];
    __syncthreads();

    const int m = t >> 4, n4 = (t & 15) * 4;
    v4f s = (v4f){0.f, 0.f, 0.f, 0.f};
#pragma unroll
    for (int ww = 0; ww < 4; ++ww) s += *(const v4f*)&cacc[ww][m][n4];

#pragma unroll
    for (int e = 0; e < 4; ++e)        // transposed store: gT[hd][node]
        gT[(size_t)(n4 + e) * NN + i0 + m] = f2h16(s[e]);

    float pl = s.x * al[n4] + s.y * al[n4 + 1] + s.z * al[n4 + 2] + s.w * al[n4 + 3];
    float pr = s.x * ar[n4] + s.y * ar[n4 + 1] + s.z * ar[n4 + 2] + s.w * ar[n4 + 3];
    pl += __shfl_xor(pl, 1, 64);
    pr += __shfl_xor(pr, 1, 64);
    if ((t & 1) == 0) {
        const int h = (t & 15) >> 1;
        const int node = i0 + m;
        eB[h * NN + node] = f2h16(exp2f(pr * LOG2E));          // exp(sr)
        eD[h * NN + node] = f2h16(exp2f(0.2f * pr * LOG2E));   // exp(0.2 sr)
        Rw[node * NH + h] = exp2f(-0.8f * pl * LOG2E);         // exp(-0.8 sl)
    }
}

// ---------------- kernel 2: MFMA flash-attn, 2 heads per wave ----------------
// grid (256, 4): x = 16-row i-block, y = j-split (1024 j, 8 chunks of 128).
// Wave w computes heads {w, w+4} — edge mask decode (sbfe+perm) is head-
// independent and shared; edge loaded ONCE per i-block (was twice in R12).
// P'[i,j] = max(B_j, R_i*D_j); ones row in B col 8 gives denominator.
__global__ __launch_bounds__(256, 4) void k_attn(
    const int* __restrict__ edge, const short* __restrict__ gT,
    const short* __restrict__ eB, const short* __restrict__ eD,
    const float* __restrict__ Rw,
    float* __restrict__ numw, float* __restrict__ denw)
{
    __shared__ __align__(16) short Gt[2][65][136];  // all 64 G-dims + ones row
    __shared__ __align__(16) short sB[2][8][136];   // exp(sr) fp16, 8 heads
    __shared__ __align__(16) short sD[2][8][136];   // exp(0.2 sr) fp16
    __shared__ u32 mA[2][16][4];                    // even-j mask words per row
    __shared__ u32 mB[2][16][4];                    // odd-j (pad to 4)

    const int t = threadIdx.x, lane = t & 63, w = t >> 6;
    const int ml = lane & 15, quad = lane >> 4;
    const int i0 = blockIdx.x * 16;
    const int js = blockIdx.y;
    const int jbase = js * (NN / NJS);
    const int h0 = w, h1 = w + 4;

    h2 Ri[2];
    {
        const f16 r0 = (f16)Rw[(i0 + ml) * NH + h0];
        const f16 r1 = (f16)Rw[(i0 + ml) * NH + h1];
        Ri[0] = (h2){r0, r0};
        Ri[1] = (h2){r1, r1};
    }

    if (t < 136) { Gt[0][64][t] = 0x3C00; Gt[1][64][t] = 0x3C00; }  // fp16 1.0

    const int grow = t >> 3, gseg = (t & 7) * 16;   // G: rows grow, grow+32
    const int bh = (t >> 3) & 7, bseg = (t & 7) * 16;  // B/D: 8 heads x 128 f16
    const int erow = w * 4;                          // edge rows erow..erow+3

    {   // stage chunk 0 (everything before compute)
        const int j0 = jbase;
        *(uint4*)&Gt[0][grow][gseg]          = *(const uint4*)&gT[grow * NN + j0 + gseg];
        *(uint4*)&Gt[0][grow][gseg + 8]      = *(const uint4*)&gT[grow * NN + j0 + gseg + 8];
        *(uint4*)&Gt[0][grow + 32][gseg]     = *(const uint4*)&gT[(grow + 32) * NN + j0 + gseg];
        *(uint4*)&Gt[0][grow + 32][gseg + 8] = *(const uint4*)&gT[(grow + 32) * NN + j0 + gseg + 8];
        if (t < 64) {
            *(uint4*)&sB[0][bh][bseg]     = *(const uint4*)&eB[bh * NN + j0 + bseg];
            *(uint4*)&sB[0][bh][bseg + 8] = *(const uint4*)&eB[bh * NN + j0 + bseg + 8];
        } else if (t < 128) {
            *(uint4*)&sD[0][bh][bseg]     = *(const uint4*)&eD[bh * NN + j0 + bseg];
            *(uint4*)&sD[0][bh][bseg + 8] = *(const uint4*)&eD[bh * NN + j0 + bseg + 8];
        }
#pragma unroll
        for (int rr = 0; rr < 4; ++rr) {
            const int row = erow + rr;
            const int2 e2 = *(const int2*)&edge[(i0 + row) * NN + j0 + 2 * lane];
            const u64 bA = __ballot(e2.x != 0);
            const u64 bB = __ballot(e2.y != 0);
            if (lane == 0)  { mA[0][row][0] = (u32)bA;         mB[0][row][0] = (u32)bB; }
            if (lane == 32) { mA[0][row][1] = (u32)(bA >> 32); mB[0][row][1] = (u32)(bB >> 32); }
        }
    }
    __syncthreads();

    v4f acc[2];
    acc[0] = (v4f){0.f, 0.f, 0.f, 0.f};
    acc[1] = (v4f){0.f, 0.f, 0.f, 0.f};

    const int qb4 = quad * 4;
    const int brow0 = (ml < 8) ? (h0 * 8 + ml) : 64;
    const int brow1 = (ml < 8) ? (h1 * 8 + ml) : 64;

    for (int c = 0; c < NCHK; ++c) {
        const int cb = c & 1, nb = cb ^ 1;
        const bool pf = (c + 1) < NCHK;
        uint4 pg[4], pbd0, pbd1; int2 pe[4];
        if (pf) {   // prefetch next chunk IN FULL (G + B/D + all edge rows)
            const int j0 = jbase + (c + 1) * 128;
            pg[0] = *(const uint4*)&gT[grow * NN + j0 + gseg];
            pg[1] = *(const uint4*)&gT[grow * NN + j0 + gseg + 8];
            pg[2] = *(const uint4*)&gT[(grow + 32) * NN + j0 + gseg];
            pg[3] = *(const uint4*)&gT[(grow + 32) * NN + j0 + gseg + 8];
            if (t < 64) {
                pbd0 = *(const uint4*)&eB[bh * NN + j0 + bseg];
                pbd1 = *(const uint4*)&eB[bh * NN + j0 + bseg + 8];
            } else if (t < 128) {
                pbd0 = *(const uint4*)&eD[bh * NN + j0 + bseg];
                pbd1 = *(const uint4*)&eD[bh * NN + j0 + bseg + 8];
            }
#pragma unroll
            for (int rr = 0; rr < 4; ++rr)
                pe[rr] = *(const int2*)&edge[(i0 + erow + rr) * NN + j0 + 2 * lane];
        }
        // ---- compute on buffer cb: mask decoded once, used for 2 heads ----
        const uint2 wa = *(const uint2*)&mA[cb][ml][0];
        const uint2 wb = *(const uint2*)&mB[cb][ml][0];
#pragma unroll
        for (int s = 0; s < 4; ++s) {
            const uint4 bu0 = *(const uint4*)&sB[cb][h0][s * 32 + quad * 8];
            const uint4 du0 = *(const uint4*)&sD[cb][h0][s * 32 + quad * 8];
            const uint4 bu1 = *(const uint4*)&sB[cb][h1][s * 32 + quad * 8];
            const uint4 du1 = *(const uint4*)&sD[cb][h1][s * 32 + quad * 8];
            const uint4 gu0 = *(const uint4*)&Gt[cb][brow0][s * 32 + quad * 8];
            const uint4 gu1 = *(const uint4*)&Gt[cb][brow1][s * 32 + quad * 8];
            const int base = ((s & 1) << 4) + qb4;
            const u32 WA = ((s >> 1) ? wa.y : wa.x) >> base;
            const u32 WB = ((s >> 1) ? wb.y : wb.x) >> base;
            u32 m[4];
#pragma unroll
            for (int k = 0; k < 4; ++k) {
                const int ea = SBFE1(WA, k);            // 0 or 0xFFFFFFFF
                const int eb = SBFE1(WB, k);
                m[k] = __builtin_amdgcn_perm((u32)eb, (u32)ea, 0x05040100u);
            }
            u32 aw0[4], aw1[4];
#pragma unroll
            for (int k = 0; k < 4; ++k) {
                const u32 rd0 = h22u(Ri[0] * u2h2((&du0.x)[k]));   // v_pk_mul_f16
                const u32 rd1 = h22u(Ri[1] * u2h2((&du1.x)[k]));
                u32 p0, p1;
                asm("v_pk_max_f16 %0, %1, %2" : "=v"(p0) : "v"(rd0), "v"((&bu0.x)[k]));
                asm("v_pk_max_f16 %0, %1, %2" : "=v"(p1) : "v"(rd1), "v"((&bu1.x)[k]));
                aw0[k] = p0 & m[k];
                aw1[k] = p1 & m[k];
            }
            union { uint4 u; f16x8 h; } a0u, a1u, g0u, g1u;
            a0u.u = (uint4){aw0[0], aw0[1], aw0[2], aw0[3]};
            a1u.u = (uint4){aw1[0], aw1[1], aw1[2], aw1[3]};
            g0u.u = gu0; g1u.u = gu1;
            acc[0] = __builtin_amdgcn_mfma_f32_16x16x32_f16(a0u.h, g0u.h, acc[0], 0, 0, 0);
            acc[1] = __builtin_amdgcn_mfma_f32_16x16x32_f16(a1u.h, g1u.h, acc[1], 0, 0, 0);
        }
        if (pf) {   // drain prefetched registers into buffer nb (no new loads)
            *(uint4*)&Gt[nb][grow][gseg]          = pg[0];
            *(uint4*)&Gt[nb][grow][gseg + 8]      = pg[1];
            *(uint4*)&Gt[nb][grow + 32][gseg]     = pg[2];
            *(uint4*)&Gt[nb][grow + 32][gseg + 8] = pg[3];
            if (t < 64) {
                *(uint4*)&sB[nb][bh][bseg]     = pbd0;
                *(uint4*)&sB[nb][bh][bseg + 8] = pbd1;
            } else if (t < 128) {
                *(uint4*)&sD[nb][bh][bseg]     = pbd0;
                *(uint4*)&sD[nb][bh][bseg + 8] = pbd1;
            }
#pragma unroll
            for (int rr = 0; rr < 4; ++rr) {
                const int row = erow + rr;
                const u64 bA = __ballot(pe[rr].x != 0);
                const u64 bB = __ballot(pe[rr].y != 0);
                if (lane == 0)  { mA[nb][row][0] = (u32)bA;         mB[nb][row][0] = (u32)bB; }
                if (lane == 32) { mA[nb][row][1] = (u32)(bA >> 32); mB[nb][row][1] = (u32)(bB >> 32); }
            }
        }
        __syncthreads();
    }

    // C layout: col = ml (0..7 dims, 8 = denominator), row = quad*4 + r
    float* nw = numw + (size_t)js * NN * HD;
    float* dw = denw + (size_t)js * NN * NH;
    const int ibase = i0 + quad * 4;
#pragma unroll
    for (int hh = 0; hh < 2; ++hh) {
        const int h = w + hh * 4;
#pragma unroll
        for (int r = 0; r < 4; ++r) {
            if (ml < 8)       nw[(ibase + r) * HD + h * 8 + ml] = acc[hh][r];
            else if (ml == 8) dw[(ibase + r) * NH + h]          = acc[hh][r];
        }
    }
}

// ---------------- kernel 3: combine j-split partials, div, ELU ---------------
__global__ __launch_bounds__(256) void k_comb(
    const float* __restrict__ numw, const float* __restrict__ denw,
    float* __restrict__ out)
{
    const int gid = blockIdx.x * 256 + threadIdx.x;   // 0 .. NN*HD-1
    const int i = gid >> 6, h = (gid & 63) >> 3;
    float num = 0.f, den = 0.f;
#pragma unroll
    for (int s = 0; s < NJS; ++s) {
        num += numw[s * NN * HD + gid];
        den += denw[s * NN * NH + i * NH + h];
    }
    float x = num / den;
    out[gid] = (x > 0.f) ? x : (__expf(x) - 1.f);     // ELU
}

extern "C" void kernel_launch(void* const* d_in, const int* in_sizes, int n_in,
                              void* d_out, int out_size, void* d_ws, size_t ws_size,
                              hipStream_t stream) {
    const float* vert = (const float*)d_in[0];
    const int*   edge = (const int*)d_in[1];
    const float* W    = (const float*)d_in[2];
    const float* al   = (const float*)d_in[3];
    const float* ar   = (const float*)d_in[4];
    float* out = (float*)d_out;

    char* ws = (char*)d_ws;
    short* gT   = (short*)ws;                          // 512 KB f16 g^T
    short* eB   = (short*)(ws + 512 * 1024);           // 64 KB
    short* eD   = (short*)(ws + 576 * 1024);           // 64 KB
    float* Rw   = (float*)(ws + 640 * 1024);           // 128 KB
    short* Wt   = (short*)(ws + 768 * 1024);           // 184 KB
    float* numw = (float*)(ws + 1024 * 1024);          // 4 MB (4 splits)
    float* denw = (float*)(ws + 5 * 1024 * 1024);      // 512 KB

    hipLaunchKernelGGL(k_wprep, dim3(23), dim3(256), 0, stream, W, Wt);
    hipLaunchKernelGGL(k_gemm, dim3(NN / 16), dim3(256), 0, stream,
                       vert, Wt, al, ar, gT, eB, eD, Rw);
    hipLaunchKernelGGL(k_attn, dim3(NN / 16, NJS), dim3(256), 0, stream,
                       edge, gT, eB, eD, Rw, numw, denw);
    hipLaunchKernelGGL(k_comb, dim3(NN * HD / 256), dim3(256), 0, stream,
                       numw, denw, out);
}